// Round 4
// baseline (236.449 us; speedup 1.0000x reference)
//
#include <hip/hip_runtime.h>

typedef unsigned short u16;
typedef short short8 __attribute__((ext_vector_type(8)));
typedef float f32x4 __attribute__((ext_vector_type(4)));
typedef float f4 __attribute__((ext_vector_type(4)));

#define MFMA16(a, b, c) __builtin_amdgcn_mfma_f32_16x16x32_bf16(a, b, c, 0, 0, 0)

__device__ inline u16 f2bf(float f) {
    unsigned int v = __builtin_bit_cast(unsigned int, f);
    unsigned int r = (v + 0x7FFFu + ((v >> 16) & 1u)) >> 16;
    return (u16)r;
}

// ---------------------------------------------------------------------------
// Kernel 1: fused spatial-reduction conv + bias + LayerNorm + K/V projection.
// Inputs fp32; converted to bf16 while staging into LDS. 32 blocks x 256 thr;
// block owns 64 kv tokens, full K=4096 reduction (64 taps of BK=64), LN in
// LDS, K/V MFMA projections. Writes k[b,t,d], vT[b,d,t] (bf16) into ws.
// ---------------------------------------------------------------------------
__global__ __launch_bounds__(256) void srkv_kernel(
    const float* __restrict__ x, const float* __restrict__ Wsr,
    const float* __restrict__ bsr,
    const float* __restrict__ gamma, const float* __restrict__ beta,
    const float* __restrict__ Wk, const float* __restrict__ bk,
    const float* __restrict__ Wv, const float* __restrict__ bv,
    u16* __restrict__ kbuf, u16* __restrict__ vTbuf)
{
    const int tid  = threadIdx.x;
    const int wave = tid >> 6;
    const int lane = tid & 63;
    const int l15  = lane & 15;
    const int quad = lane >> 4;
    const int token0 = blockIdx.x * 64;

    __shared__ u16   sA[64 * 72];    // x-patch chunk [token][ci] bf16
    __shared__ u16   sB[64 * 72];    // Wsr chunk transposed [co][kk] bf16
    __shared__ float sXf[64 * 68];   // conv result (f32) [token][co]
    __shared__ u16   sWk[64 * 72];   // Wk^T [co][ci] bf16
    __shared__ u16   sWv[64 * 72];   // Wv^T [co][ci] bf16
    __shared__ u16   sN[64 * 72];    // normalized tile bf16 [token][ci]
    __shared__ float sMean[64], sInv[64];

    // stage Wk/Wv transposed once (fp32 -> bf16)
#pragma unroll
    for (int p = 0; p < 4; ++p) {
        int idx = p * 256 + tid;             // 0..1023
        int ci = idx >> 4, c4 = (idx & 15) * 4;
        f4 wk = *(const f4*)(Wk + ci * 64 + c4);
        f4 wv = *(const f4*)(Wv + ci * 64 + c4);
#pragma unroll
        for (int j = 0; j < 4; ++j) {
            sWk[(c4 + j) * 72 + ci] = f2bf(wk[j]);
            sWv[(c4 + j) * 72 + ci] = f2bf(wv[j]);
        }
    }

    f32x4 acc[4];
#pragma unroll
    for (int nt = 0; nt < 4; ++nt) { acc[nt][0]=0.f; acc[nt][1]=0.f; acc[nt][2]=0.f; acc[nt][3]=0.f; }

    for (int cell = 0; cell < 64; ++cell) {   // (py,px) conv taps
        const int py = cell >> 3, px = cell & 7;
        const int k0 = cell * 64;
        __syncthreads();
        // stage A: 64 tokens x 64 input channels (fp32 -> bf16)
#pragma unroll
        for (int p = 0; p < 4; ++p) {
            int idx = p * 256 + tid;         // 0..1023
            int r = idx >> 4, c4 = (idx & 15) * 4;
            int token = token0 + r;
            int b = token >> 8, rm = token & 255;
            int oy = rm >> 4, ox = rm & 15;
            int y = oy * 8 + py, xc = ox * 8 + px;
            f4 xv = *(const f4*)(x + ((size_t)(b * 16384 + y * 128 + xc)) * 64 + c4);
#pragma unroll
            for (int j = 0; j < 4; ++j) sA[r * 72 + c4 + j] = f2bf(xv[j]);
        }
        // stage B transposed: sB[co*72 + kk] = Wsr[(k0+kk)*64 + co]
#pragma unroll
        for (int p = 0; p < 4; ++p) {
            int idx = p * 256 + tid;
            int kk = idx >> 4, c4 = (idx & 15) * 4;
            f4 w = *(const f4*)(Wsr + (size_t)(k0 + kk) * 64 + c4);
#pragma unroll
            for (int j = 0; j < 4; ++j) sB[(c4 + j) * 72 + kk] = f2bf(w[j]);
        }
        __syncthreads();
#pragma unroll
        for (int ks = 0; ks < 2; ++ks) {
            short8 af = *(const short8*)&sA[(wave * 16 + l15) * 72 + ks * 32 + quad * 8];
#pragma unroll
            for (int nt = 0; nt < 4; ++nt) {
                short8 bf = *(const short8*)&sB[(nt * 16 + l15) * 72 + ks * 32 + quad * 8];
                acc[nt] = MFMA16(af, bf, acc[nt]);
            }
        }
    }

    // conv result + bias -> LDS (f32)
#pragma unroll
    for (int nt = 0; nt < 4; ++nt)
#pragma unroll
        for (int i = 0; i < 4; ++i) {
            int row = wave * 16 + quad * 4 + i;
            int col = nt * 16 + l15;
            sXf[row * 68 + col] = acc[nt][i] + bsr[col];
        }
    __syncthreads();

    // LayerNorm stats: thread r (<64) reduces its row serially
    if (tid < 64) {
        float sum = 0.f, sumsq = 0.f;
#pragma unroll 8
        for (int c = 0; c < 64; ++c) {
            float v = sXf[tid * 68 + c];
            sum += v; sumsq += v * v;
        }
        float mean = sum * (1.f / 64.f);
        float var  = sumsq * (1.f / 64.f) - mean * mean;
        sMean[tid] = mean;
        sInv[tid]  = rsqrtf(var + 1e-5f);
    }
    __syncthreads();

    // normalize into bf16 tile sN
#pragma unroll
    for (int j = 0; j < 16; ++j) {
        int e = j * 256 + tid;          // 0..4095
        int row = e >> 6, col = e & 63;
        float xn = (sXf[row * 68 + col] - sMean[row]) * sInv[row]
                 * gamma[col] + beta[col];
        sN[row * 72 + col] = f2bf(xn);
    }
    __syncthreads();

    // K/V projections (MFMA) + store (bf16 ws)
    f32x4 kacc[4], vacc[4];
#pragma unroll
    for (int nt = 0; nt < 4; ++nt) {
        kacc[nt][0]=0.f; kacc[nt][1]=0.f; kacc[nt][2]=0.f; kacc[nt][3]=0.f;
        vacc[nt][0]=0.f; vacc[nt][1]=0.f; vacc[nt][2]=0.f; vacc[nt][3]=0.f;
    }
#pragma unroll
    for (int ks = 0; ks < 2; ++ks) {
        short8 af = *(const short8*)&sN[(wave * 16 + l15) * 72 + ks * 32 + quad * 8];
#pragma unroll
        for (int nt = 0; nt < 4; ++nt) {
            short8 bk_ = *(const short8*)&sWk[(nt * 16 + l15) * 72 + ks * 32 + quad * 8];
            kacc[nt] = MFMA16(af, bk_, kacc[nt]);
            short8 bv_ = *(const short8*)&sWv[(nt * 16 + l15) * 72 + ks * 32 + quad * 8];
            vacc[nt] = MFMA16(af, bv_, vacc[nt]);
        }
    }
#pragma unroll
    for (int nt = 0; nt < 4; ++nt)
#pragma unroll
        for (int i = 0; i < 4; ++i) {
            int token = token0 + wave * 16 + quad * 4 + i;
            int d = nt * 16 + l15;
            kbuf[(size_t)token * 64 + d] = f2bf(kacc[nt][i] + bk[d]);
            int b = token >> 8, t = token & 255;
            vTbuf[(size_t)b * 16384 + d * 256 + t] = f2bf(vacc[nt][i] + bv[d]);
        }
}

// ---------------------------------------------------------------------------
// Kernel 2: fused q-proj + attention + out-proj. fp32 in/out, bf16 MFMA.
// 2048 blocks (8 batches x 256 q-tiles of 64 rows), 4 waves, 16 rows/wave.
// Nkv=256 held entirely in registers through softmax.
// ---------------------------------------------------------------------------
__global__ __launch_bounds__(256) void attn_kernel(
    const float* __restrict__ x, const float* __restrict__ Wq,
    const float* __restrict__ bq, const float* __restrict__ Wp,
    const float* __restrict__ bp, const u16* __restrict__ kbuf,
    const u16* __restrict__ vTbuf, float* __restrict__ out)
{
    const int batch = blockIdx.x >> 8;
    const int row0  = (blockIdx.x & 255) * 64;
    const int tid  = threadIdx.x;
    const int wave = tid >> 6;
    const int lane = tid & 63;
    const int l15  = lane & 15;
    const int quad = lane >> 4;

    __shared__ u16 sK[256 * 72];      // k[token][d], stride 72
    __shared__ u16 sV[64 * 264];      // vT[d][token], stride 264
    __shared__ u16 sQ[64 * 72];       // x-tile, then q-tile (per-wave rows)
    __shared__ u16 sWq[64 * 72];      // Wq^T [co][ci]
    __shared__ u16 sWp[64 * 72];      // Wp^T [co][ci]
    __shared__ u16 sP[4][16 * 72];    // per-wave P / O scratch

    // ---- cooperative staging ----
#pragma unroll
    for (int p = 0; p < 8; ++p) {
        int idx = p * 256 + tid; int tt = idx >> 3, seg = idx & 7;
        *(short8*)&sK[tt * 72 + seg * 8] =
            *(const short8*)(kbuf + ((size_t)(batch * 256 + tt)) * 64 + seg * 8);
    }
#pragma unroll
    for (int p = 0; p < 8; ++p) {
        int idx = p * 256 + tid; int d = idx >> 5, seg = idx & 31;
        *(short8*)&sV[d * 264 + seg * 8] =
            *(const short8*)(vTbuf + ((size_t)(batch * 64 + d)) * 256 + seg * 8);
    }
#pragma unroll
    for (int p = 0; p < 4; ++p) {
        int idx = p * 256 + tid; int r = idx >> 4, c4 = (idx & 15) * 4;
        f4 xv = *(const f4*)(x + ((size_t)(batch * 16384 + row0 + r)) * 64 + c4);
#pragma unroll
        for (int j = 0; j < 4; ++j) sQ[r * 72 + c4 + j] = f2bf(xv[j]);
    }
#pragma unroll
    for (int p = 0; p < 4; ++p) {
        int idx = p * 256 + tid; int ci = idx >> 4, c4 = (idx & 15) * 4;
        f4 wq = *(const f4*)(Wq + ci * 64 + c4);
        f4 wp = *(const f4*)(Wp + ci * 64 + c4);
#pragma unroll
        for (int j = 0; j < 4; ++j) {
            sWq[(c4 + j) * 72 + ci] = f2bf(wq[j]);
            sWp[(c4 + j) * 72 + ci] = f2bf(wp[j]);
        }
    }
    __syncthreads();

    // ---- q projection (per-wave rows; sQ holds x, rewritten with q) ----
    {
        f32x4 qacc[4];
#pragma unroll
        for (int nt = 0; nt < 4; ++nt) { qacc[nt][0]=0.f; qacc[nt][1]=0.f; qacc[nt][2]=0.f; qacc[nt][3]=0.f; }
#pragma unroll
        for (int ks = 0; ks < 2; ++ks) {
            short8 af = *(const short8*)&sQ[(wave * 16 + l15) * 72 + ks * 32 + quad * 8];
#pragma unroll
            for (int nt = 0; nt < 4; ++nt) {
                short8 bf = *(const short8*)&sWq[(nt * 16 + l15) * 72 + ks * 32 + quad * 8];
                qacc[nt] = MFMA16(af, bf, qacc[nt]);
            }
        }
#pragma unroll
        for (int nt = 0; nt < 4; ++nt)
#pragma unroll
            for (int i = 0; i < 4; ++i) {
                int r = wave * 16 + quad * 4 + i, cc = nt * 16 + l15;
                float qv = (qacc[nt][i] + bq[cc]) * 0.125f;  // fold 1/sqrt(64)
                sQ[r * 72 + cc] = f2bf(qv);
            }
    }
    __syncthreads();

    // ---- S = q @ k^T : 16 n-tiles of 16 kv tokens ----
    f32x4 s_acc[16];
#pragma unroll
    for (int nt = 0; nt < 16; ++nt) { s_acc[nt][0]=0.f; s_acc[nt][1]=0.f; s_acc[nt][2]=0.f; s_acc[nt][3]=0.f; }
    {
        short8 aq0 = *(const short8*)&sQ[(wave * 16 + l15) * 72 + quad * 8];
        short8 aq1 = *(const short8*)&sQ[(wave * 16 + l15) * 72 + 32 + quad * 8];
#pragma unroll
        for (int nt = 0; nt < 16; ++nt) {
            short8 b0 = *(const short8*)&sK[(nt * 16 + l15) * 72 + quad * 8];
            s_acc[nt] = MFMA16(aq0, b0, s_acc[nt]);
            short8 b1 = *(const short8*)&sK[(nt * 16 + l15) * 72 + 32 + quad * 8];
            s_acc[nt] = MFMA16(aq1, b1, s_acc[nt]);
        }
    }

    // ---- softmax over 256 (row = quad*4+i, cols spread over l15 x 16 tiles) ----
    float lrow[4];
#pragma unroll
    for (int i = 0; i < 4; ++i) {
        float m = -1e30f;
#pragma unroll
        for (int nt = 0; nt < 16; ++nt) m = fmaxf(m, s_acc[nt][i]);
#pragma unroll
        for (int msk = 1; msk < 16; msk <<= 1) m = fmaxf(m, __shfl_xor(m, msk, 64));
        float l = 0.f;
#pragma unroll
        for (int nt = 0; nt < 16; ++nt) {
            float pexp = __expf(s_acc[nt][i] - m);
            s_acc[nt][i] = pexp;
            l += pexp;
        }
#pragma unroll
        for (int msk = 1; msk < 16; msk <<= 1) l += __shfl_xor(l, msk, 64);
        lrow[i] = l;
    }

    // ---- O = P @ V, streamed in 4 chunks of 64 kv tokens ----
    f32x4 o_acc[4];
#pragma unroll
    for (int nt = 0; nt < 4; ++nt) { o_acc[nt][0]=0.f; o_acc[nt][1]=0.f; o_acc[nt][2]=0.f; o_acc[nt][3]=0.f; }
    for (int ch = 0; ch < 4; ++ch) {
#pragma unroll
        for (int t = 0; t < 4; ++t) {
            int nt = ch * 4 + t;
#pragma unroll
            for (int i = 0; i < 4; ++i)
                sP[wave][(quad * 4 + i) * 72 + t * 16 + l15] = f2bf(s_acc[nt][i]);
        }
        __syncthreads();
#pragma unroll
        for (int ks = 0; ks < 2; ++ks) {
            short8 ap = *(const short8*)&sP[wave][l15 * 72 + ks * 32 + quad * 8];
#pragma unroll
            for (int nt = 0; nt < 4; ++nt) {
                short8 bv_ = *(const short8*)&sV[(nt * 16 + l15) * 264 + ch * 64 + ks * 32 + quad * 8];
                o_acc[nt] = MFMA16(ap, bv_, o_acc[nt]);
            }
        }
        __syncthreads();
    }

    // ---- epilogue: scale by 1/l, out-proj with Wp, + bp, store fp32 ----
#pragma unroll
    for (int nt = 0; nt < 4; ++nt)
#pragma unroll
        for (int i = 0; i < 4; ++i) {
            float ov = o_acc[nt][i] * (1.0f / lrow[i]);
            sP[wave][(quad * 4 + i) * 72 + nt * 16 + l15] = f2bf(ov);
        }
    __syncthreads();
    {
        f32x4 f_acc[4];
#pragma unroll
        for (int nt = 0; nt < 4; ++nt) { f_acc[nt][0]=0.f; f_acc[nt][1]=0.f; f_acc[nt][2]=0.f; f_acc[nt][3]=0.f; }
#pragma unroll
        for (int ks = 0; ks < 2; ++ks) {
            short8 ao = *(const short8*)&sP[wave][l15 * 72 + ks * 32 + quad * 8];
#pragma unroll
            for (int nt = 0; nt < 4; ++nt) {
                short8 bf = *(const short8*)&sWp[(nt * 16 + l15) * 72 + ks * 32 + quad * 8];
                f_acc[nt] = MFMA16(ao, bf, f_acc[nt]);
            }
        }
#pragma unroll
        for (int nt = 0; nt < 4; ++nt)
#pragma unroll
            for (int i = 0; i < 4; ++i) {
                int r = row0 + wave * 16 + quad * 4 + i, cc = nt * 16 + l15;
                out[((size_t)batch * 16384 + r) * 64 + cc] = f_acc[nt][i] + bp[cc];
            }
    }
}

// ---------------------------------------------------------------------------
extern "C" void kernel_launch(void* const* d_in, const int* in_sizes, int n_in,
                              void* d_out, int out_size, void* d_ws, size_t ws_size,
                              hipStream_t stream) {
    const float* x     = (const float*)d_in[0];
    const float* Wq    = (const float*)d_in[1];
    const float* bq    = (const float*)d_in[2];
    const float* Wk    = (const float*)d_in[3];
    const float* bk    = (const float*)d_in[4];
    const float* Wv    = (const float*)d_in[5];
    const float* bv    = (const float*)d_in[6];
    const float* Wsr   = (const float*)d_in[7];
    const float* bsr   = (const float*)d_in[8];
    const float* gamma = (const float*)d_in[9];
    const float* beta  = (const float*)d_in[10];
    const float* Wp    = (const float*)d_in[11];
    const float* bp    = (const float*)d_in[12];

    u16* kbuf  = (u16*)d_ws;                      // 2048*64 bf16 = 256 KB
    u16* vTbuf = kbuf + (size_t)2048 * 64;        // 8*64*256 bf16 = 256 KB
    float* out = (float*)d_out;

    srkv_kernel<<<32, 256, 0, stream>>>(x, Wsr, bsr, gamma, beta, Wk, bk, Wv, bv, kbuf, vTbuf);
    attn_kernel<<<2048, 256, 0, stream>>>(x, Wq, bq, Wp, bp, kbuf, vTbuf, out);
}

// Round 5
// 152.900 us; speedup vs baseline: 1.5464x; 1.5464x over previous
//
#include <hip/hip_runtime.h>

typedef unsigned short u16;
typedef short short8 __attribute__((ext_vector_type(8)));
typedef short short4v __attribute__((ext_vector_type(4)));
typedef float f32x4 __attribute__((ext_vector_type(4)));
typedef float f4 __attribute__((ext_vector_type(4)));

#define MFMA16(a, b, c) __builtin_amdgcn_mfma_f32_16x16x32_bf16(a, b, c, 0, 0, 0)

__device__ inline u16 f2bf(float f) {
    unsigned int v = __builtin_bit_cast(unsigned int, f);
    unsigned int r = (v + 0x7FFFu + ((v >> 16) & 1u)) >> 16;
    return (u16)r;
}

// ---------------------------------------------------------------------------
// Kernel 0: one-time weight prep. Transpose Wsr (per tap), Wq, Wp to bf16
// [co][ci] row-major in ws. Grid 66: bid<64 = tap, 64 = Wq, 65 = Wp.
// ---------------------------------------------------------------------------
__global__ __launch_bounds__(256) void prep_kernel(
    const float* __restrict__ Wsr, const float* __restrict__ Wq,
    const float* __restrict__ Wp,
    u16* __restrict__ WsrT, u16* __restrict__ WqT, u16* __restrict__ WpT)
{
    const int bid = blockIdx.x;
    const int tid = threadIdx.x;
    __shared__ float sT[64 * 65];   // stride 65: 8*65 % 32 != 0 -> low conflicts
    const float* src;
    u16* dst;
    if (bid < 64)      { src = Wsr + (size_t)bid * 4096; dst = WsrT + (size_t)bid * 4096; }
    else if (bid == 64){ src = Wq;  dst = WqT; }
    else               { src = Wp;  dst = WpT; }
#pragma unroll
    for (int p = 0; p < 4; ++p) {
        int idx = p * 256 + tid;          // 0..1023
        int r = idx >> 4, c4 = (idx & 15) * 4;
        f4 v = *(const f4*)(src + r * 64 + c4);
#pragma unroll
        for (int j = 0; j < 4; ++j) sT[r * 65 + c4 + j] = v[j];
    }
    __syncthreads();
#pragma unroll
    for (int p = 0; p < 2; ++p) {
        int idx = p * 256 + tid;          // 0..511
        int co = idx >> 3, g = (idx & 7) * 8;
        short8 o;
#pragma unroll
        for (int j = 0; j < 8; ++j) o[j] = (short)f2bf(sT[(g + j) * 65 + co]);
        *(short8*)(dst + (size_t)co * 64 + g) = o;
    }
}

// ---------------------------------------------------------------------------
// Kernel 1: split-K conv partials. Grid 256 = 8 ksplits x 32 mtiles.
// Block: 64 tokens x 64 co, 8 taps of BK=64. fp32 partials [8][2048][64].
// ---------------------------------------------------------------------------
__global__ __launch_bounds__(256) void conv_partial_kernel(
    const float* __restrict__ x, const u16* __restrict__ WsrT,
    float* __restrict__ partials)
{
    const int mtile  = blockIdx.x & 31;
    const int ksplit = blockIdx.x >> 5;
    const int tid  = threadIdx.x;
    const int wave = tid >> 6;
    const int lane = tid & 63;
    const int l15  = lane & 15;
    const int quad = lane >> 4;

    __shared__ u16 sA[64 * 72];
    __shared__ u16 sB[64 * 72];

    f32x4 acc[4];
#pragma unroll
    for (int nt = 0; nt < 4; ++nt) { acc[nt][0]=0.f; acc[nt][1]=0.f; acc[nt][2]=0.f; acc[nt][3]=0.f; }

    const int token0 = mtile * 64;
    for (int chunk = 0; chunk < 8; ++chunk) {
        const int cell = ksplit * 8 + chunk;
        const int py = cell >> 3, px = cell & 7;
        __syncthreads();
        // stage A: fp32 -> bf16, b64 LDS writes
#pragma unroll
        for (int p = 0; p < 4; ++p) {
            int idx = p * 256 + tid;      // 0..1023
            int r = idx >> 4, c4 = (idx & 15) * 4;
            int token = token0 + r;
            int b = token >> 8, rm = token & 255;
            int oy = rm >> 4, ox = rm & 15;
            int y = oy * 8 + py, xc = ox * 8 + px;
            f4 xv = *(const f4*)(x + ((size_t)(b * 16384 + y * 128 + xc)) * 64 + c4);
            short4v s;
#pragma unroll
            for (int j = 0; j < 4; ++j) s[j] = (short)f2bf(xv[j]);
            *(short4v*)&sA[r * 72 + c4] = s;
        }
        // stage B: prepped bf16 [co][ci], straight b128 copies
#pragma unroll
        for (int p = 0; p < 2; ++p) {
            int idx = p * 256 + tid;      // 0..511
            int co = idx >> 3, g = (idx & 7) * 8;
            *(short8*)&sB[co * 72 + g] =
                *(const short8*)(WsrT + (size_t)cell * 4096 + co * 64 + g);
        }
        __syncthreads();
#pragma unroll
        for (int ks = 0; ks < 2; ++ks) {
            short8 af = *(const short8*)&sA[(wave * 16 + l15) * 72 + ks * 32 + quad * 8];
#pragma unroll
            for (int nt = 0; nt < 4; ++nt) {
                short8 bf = *(const short8*)&sB[(nt * 16 + l15) * 72 + ks * 32 + quad * 8];
                acc[nt] = MFMA16(af, bf, acc[nt]);
            }
        }
    }
    float* outp = partials + (size_t)ksplit * 131072;
#pragma unroll
    for (int nt = 0; nt < 4; ++nt)
#pragma unroll
        for (int i = 0; i < 4; ++i) {
            int row = token0 + wave * 16 + quad * 4 + i;
            outp[(size_t)row * 64 + nt * 16 + l15] = acc[nt][i];
        }
}

// ---------------------------------------------------------------------------
// Kernel 2: reduce partials + bias + LayerNorm + K/V proj (vector ALU).
// Grid 512 x 256 thr; one wave per kv token (2048 waves). No barriers.
// ---------------------------------------------------------------------------
__global__ __launch_bounds__(256) void lnkv_kernel(
    const float* __restrict__ partials, const float* __restrict__ bsr,
    const float* __restrict__ gamma, const float* __restrict__ beta,
    const float* __restrict__ Wk, const float* __restrict__ bk,
    const float* __restrict__ Wv, const float* __restrict__ bv,
    u16* __restrict__ kbuf, u16* __restrict__ vTbuf)
{
    const int wave = threadIdx.x >> 6;
    const int c    = threadIdx.x & 63;
    const int token = blockIdx.x * 4 + wave;

    float acc = 0.f;
#pragma unroll
    for (int s = 0; s < 8; ++s)
        acc += partials[(size_t)s * 131072 + (size_t)token * 64 + c];
    acc += bsr[c];

    float sum = acc, sumsq = acc * acc;
#pragma unroll
    for (int m = 1; m < 64; m <<= 1) {
        sum   += __shfl_xor(sum, m, 64);
        sumsq += __shfl_xor(sumsq, m, 64);
    }
    float mean = sum * (1.f / 64.f);
    float var  = sumsq * (1.f / 64.f) - mean * mean;
    float inv  = rsqrtf(var + 1e-5f);
    float xn   = (acc - mean) * inv * gamma[c] + beta[c];

    __shared__ float sxn[4][64];      // wave-private rows -> no barrier needed
    sxn[wave][c] = xn;

    float ka = bk[c], va = bv[c];
#pragma unroll 8
    for (int ci = 0; ci < 64; ++ci) {
        float xv = sxn[wave][ci];
        ka += xv * Wk[ci * 64 + c];
        va += xv * Wv[ci * 64 + c];
    }
    kbuf[(size_t)token * 64 + c] = f2bf(ka);
    int b = token >> 8, t = token & 255;
    vTbuf[(size_t)b * 16384 + c * 256 + t] = f2bf(va);
}

// ---------------------------------------------------------------------------
// Kernel 3: fused q-proj + attention + out-proj.
// Grid 1024 (8 batches x 128 tiles of 128 q-rows), 512 thr = 8 waves,
// 16 q-rows/wave. ONE barrier (after staging); sP / own sQ rows are
// wave-private so same-wave in-order DS ordering suffices.
// ---------------------------------------------------------------------------
__global__ __launch_bounds__(512) void attn_kernel(
    const float* __restrict__ x, const u16* __restrict__ WqT,
    const float* __restrict__ bq, const u16* __restrict__ WpT,
    const float* __restrict__ bp, const u16* __restrict__ kbuf,
    const u16* __restrict__ vTbuf, float* __restrict__ out)
{
    const int batch = blockIdx.x >> 7;
    const int row0  = (blockIdx.x & 127) * 128;
    const int tid  = threadIdx.x;
    const int wave = tid >> 6;
    const int lane = tid & 63;
    const int l15  = lane & 15;
    const int quad = lane >> 4;

    __shared__ u16 sK[256 * 72];      // 36.0 KB
    __shared__ u16 sV[64 * 264];      // 33.8 KB
    __shared__ u16 sQ[128 * 72];      // 18.0 KB
    __shared__ u16 sWq[64 * 72];      //  9.0 KB
    __shared__ u16 sWp[64 * 72];      //  9.0 KB
    __shared__ u16 sP[8][16 * 72];    // 18.0 KB  (per-wave private)

    // ---- cooperative staging (the only barrier protects these) ----
#pragma unroll
    for (int p = 0; p < 4; ++p) {
        int idx = p * 512 + tid; int tt = idx >> 3, seg = idx & 7;
        *(short8*)&sK[tt * 72 + seg * 8] =
            *(const short8*)(kbuf + ((size_t)(batch * 256 + tt)) * 64 + seg * 8);
    }
#pragma unroll
    for (int p = 0; p < 4; ++p) {
        int idx = p * 512 + tid; int d = idx >> 5, seg = idx & 31;
        *(short8*)&sV[d * 264 + seg * 8] =
            *(const short8*)(vTbuf + ((size_t)(batch * 64 + d)) * 256 + seg * 8);
    }
#pragma unroll
    for (int p = 0; p < 4; ++p) {
        int idx = p * 512 + tid; int r = idx >> 4, c4 = (idx & 15) * 4;
        f4 xv = *(const f4*)(x + ((size_t)(batch * 16384 + row0 + r)) * 64 + c4);
        short4v s;
#pragma unroll
        for (int j = 0; j < 4; ++j) s[j] = (short)f2bf(xv[j]);
        *(short4v*)&sQ[r * 72 + c4] = s;
    }
    {
        int co = tid >> 3, g = (tid & 7) * 8;
        *(short8*)&sWq[co * 72 + g] = *(const short8*)(WqT + (size_t)co * 64 + g);
        *(short8*)&sWp[co * 72 + g] = *(const short8*)(WpT + (size_t)co * 64 + g);
    }
    __syncthreads();

    // ---- q projection on own 16 rows (wave-private; no barrier) ----
    {
        f32x4 qacc[4];
#pragma unroll
        for (int nt = 0; nt < 4; ++nt) { qacc[nt][0]=0.f; qacc[nt][1]=0.f; qacc[nt][2]=0.f; qacc[nt][3]=0.f; }
#pragma unroll
        for (int ks = 0; ks < 2; ++ks) {
            short8 af = *(const short8*)&sQ[(wave * 16 + l15) * 72 + ks * 32 + quad * 8];
#pragma unroll
            for (int nt = 0; nt < 4; ++nt) {
                short8 bf = *(const short8*)&sWq[(nt * 16 + l15) * 72 + ks * 32 + quad * 8];
                qacc[nt] = MFMA16(af, bf, qacc[nt]);
            }
        }
#pragma unroll
        for (int nt = 0; nt < 4; ++nt)
#pragma unroll
            for (int i = 0; i < 4; ++i) {
                int r = wave * 16 + quad * 4 + i, cc = nt * 16 + l15;
                float qv = (qacc[nt][i] + bq[cc]) * 0.125f;   // fold 1/sqrt(64)
                sQ[r * 72 + cc] = f2bf(qv);
            }
    }

    // ---- S = q @ k^T : 16 n-tiles of 16 kv tokens ----
    f32x4 s_acc[16];
#pragma unroll
    for (int nt = 0; nt < 16; ++nt) { s_acc[nt][0]=0.f; s_acc[nt][1]=0.f; s_acc[nt][2]=0.f; s_acc[nt][3]=0.f; }
    {
        short8 aq0 = *(const short8*)&sQ[(wave * 16 + l15) * 72 + quad * 8];
        short8 aq1 = *(const short8*)&sQ[(wave * 16 + l15) * 72 + 32 + quad * 8];
#pragma unroll
        for (int nt = 0; nt < 16; ++nt) {
            short8 b0 = *(const short8*)&sK[(nt * 16 + l15) * 72 + quad * 8];
            s_acc[nt] = MFMA16(aq0, b0, s_acc[nt]);
            short8 b1 = *(const short8*)&sK[(nt * 16 + l15) * 72 + 32 + quad * 8];
            s_acc[nt] = MFMA16(aq1, b1, s_acc[nt]);
        }
    }

    // ---- softmax over 256 ----
    float lrow[4];
#pragma unroll
    for (int i = 0; i < 4; ++i) {
        float m = -1e30f;
#pragma unroll
        for (int nt = 0; nt < 16; ++nt) m = fmaxf(m, s_acc[nt][i]);
#pragma unroll
        for (int msk = 1; msk < 16; msk <<= 1) m = fmaxf(m, __shfl_xor(m, msk, 64));
        float l = 0.f;
#pragma unroll
        for (int nt = 0; nt < 16; ++nt) {
            float pexp = __expf(s_acc[nt][i] - m);
            s_acc[nt][i] = pexp;
            l += pexp;
        }
#pragma unroll
        for (int msk = 1; msk < 16; msk <<= 1) l += __shfl_xor(l, msk, 64);
        lrow[i] = l;
    }

    // ---- O = P @ V in 4 chunks; sP is wave-private (no barriers) ----
    f32x4 o_acc[4];
#pragma unroll
    for (int nt = 0; nt < 4; ++nt) { o_acc[nt][0]=0.f; o_acc[nt][1]=0.f; o_acc[nt][2]=0.f; o_acc[nt][3]=0.f; }
    for (int ch = 0; ch < 4; ++ch) {
#pragma unroll
        for (int t = 0; t < 4; ++t) {
            int nt = ch * 4 + t;
#pragma unroll
            for (int i = 0; i < 4; ++i)
                sP[wave][(quad * 4 + i) * 72 + t * 16 + l15] = f2bf(s_acc[nt][i]);
        }
#pragma unroll
        for (int ks = 0; ks < 2; ++ks) {
            short8 ap = *(const short8*)&sP[wave][l15 * 72 + ks * 32 + quad * 8];
#pragma unroll
            for (int nt = 0; nt < 4; ++nt) {
                short8 bv_ = *(const short8*)&sV[(nt * 16 + l15) * 264 + ch * 64 + ks * 32 + quad * 8];
                o_acc[nt] = MFMA16(ap, bv_, o_acc[nt]);
            }
        }
    }

    // ---- epilogue: 1/l scale, out-proj, + bp, fp32 store ----
#pragma unroll
    for (int nt = 0; nt < 4; ++nt)
#pragma unroll
        for (int i = 0; i < 4; ++i) {
            float ov = o_acc[nt][i] * (1.0f / lrow[i]);
            sP[wave][(quad * 4 + i) * 72 + nt * 16 + l15] = f2bf(ov);
        }
    {
        f32x4 f_acc[4];
#pragma unroll
        for (int nt = 0; nt < 4; ++nt) { f_acc[nt][0]=0.f; f_acc[nt][1]=0.f; f_acc[nt][2]=0.f; f_acc[nt][3]=0.f; }
#pragma unroll
        for (int ks = 0; ks < 2; ++ks) {
            short8 ao = *(const short8*)&sP[wave][l15 * 72 + ks * 32 + quad * 8];
#pragma unroll
            for (int nt = 0; nt < 4; ++nt) {
                short8 bf = *(const short8*)&sWp[(nt * 16 + l15) * 72 + ks * 32 + quad * 8];
                f_acc[nt] = MFMA16(ao, bf, f_acc[nt]);
            }
        }
#pragma unroll
        for (int nt = 0; nt < 4; ++nt)
#pragma unroll
            for (int i = 0; i < 4; ++i) {
                int r = row0 + wave * 16 + quad * 4 + i, cc = nt * 16 + l15;
                out[((size_t)batch * 16384 + r) * 64 + cc] = f_acc[nt][i] + bp[cc];
            }
    }
}

// ---------------------------------------------------------------------------
extern "C" void kernel_launch(void* const* d_in, const int* in_sizes, int n_in,
                              void* d_out, int out_size, void* d_ws, size_t ws_size,
                              hipStream_t stream) {
    const float* x     = (const float*)d_in[0];
    const float* Wq    = (const float*)d_in[1];
    const float* bq    = (const float*)d_in[2];
    const float* Wk    = (const float*)d_in[3];
    const float* bk    = (const float*)d_in[4];
    const float* Wv    = (const float*)d_in[5];
    const float* bv    = (const float*)d_in[6];
    const float* Wsr   = (const float*)d_in[7];
    const float* bsr   = (const float*)d_in[8];
    const float* gamma = (const float*)d_in[9];
    const float* beta  = (const float*)d_in[10];
    const float* Wp    = (const float*)d_in[11];
    const float* bp    = (const float*)d_in[12];

    char* w = (char*)d_ws;
    float* partials = (float*)w;                         // 8*2048*64 f32 = 4 MB
    u16* kbuf  = (u16*)(w + 4194304);                    // 256 KB
    u16* vTbuf = (u16*)(w + 4194304 + 262144);           // 256 KB
    u16* WsrT  = (u16*)(w + 4194304 + 524288);           // 512 KB
    u16* WqT   = (u16*)(w + 4194304 + 524288 + 524288);  // 8 KB
    u16* WpT   = (u16*)(w + 4194304 + 524288 + 524288 + 8192);
    float* out = (float*)d_out;

    prep_kernel<<<66, 256, 0, stream>>>(Wsr, Wq, Wp, WsrT, WqT, WpT);
    conv_partial_kernel<<<256, 256, 0, stream>>>(x, WsrT, partials);
    lnkv_kernel<<<512, 256, 0, stream>>>(partials, bsr, gamma, beta, Wk, bk, Wv, bv, kbuf, vTbuf);
    attn_kernel<<<1024, 512, 0, stream>>>(x, WqT, bq, WpT, bp, kbuf, vTbuf, out);
}

// Round 6
// 148.416 us; speedup vs baseline: 1.5931x; 1.0302x over previous
//
#include <hip/hip_runtime.h>

typedef unsigned short u16;
typedef short short8 __attribute__((ext_vector_type(8)));
typedef short short4v __attribute__((ext_vector_type(4)));
typedef float f32x4 __attribute__((ext_vector_type(4)));
typedef float f4 __attribute__((ext_vector_type(4)));

#define MFMA16(a, b, c) __builtin_amdgcn_mfma_f32_16x16x32_bf16(a, b, c, 0, 0, 0)
// K=16 variant: B-fragment layout == C/D layout -> chain MFMAs in registers
#define MFMA1K(a, b, c) __builtin_amdgcn_mfma_f32_16x16x16bf16_1k(a, b, c, 0, 0, 0)

__device__ inline u16 f2bf(float f) {
    unsigned int v = __builtin_bit_cast(unsigned int, f);
    unsigned int r = (v + 0x7FFFu + ((v >> 16) & 1u)) >> 16;
    return (u16)r;
}
__device__ inline short4v pack4(f4 v) {
    short4v r;
#pragma unroll
    for (int j = 0; j < 4; ++j) r[j] = (short)f2bf(v[j]);
    return r;
}

// ---------------------------------------------------------------------------
// Kernel 0: one-time weight prep. Transpose Wsr (per tap), Wq, Wp to bf16
// [co][ci] row-major in ws. Grid 66: bid<64 = tap, 64 = Wq, 65 = Wp.
// ---------------------------------------------------------------------------
__global__ __launch_bounds__(256) void prep_kernel(
    const float* __restrict__ Wsr, const float* __restrict__ Wq,
    const float* __restrict__ Wp,
    u16* __restrict__ WsrT, u16* __restrict__ WqT, u16* __restrict__ WpT)
{
    const int bid = blockIdx.x;
    const int tid = threadIdx.x;
    __shared__ float sT[64 * 65];
    const float* src;
    u16* dst;
    if (bid < 64)      { src = Wsr + (size_t)bid * 4096; dst = WsrT + (size_t)bid * 4096; }
    else if (bid == 64){ src = Wq;  dst = WqT; }
    else               { src = Wp;  dst = WpT; }
#pragma unroll
    for (int p = 0; p < 4; ++p) {
        int idx = p * 256 + tid;
        int r = idx >> 4, c4 = (idx & 15) * 4;
        f4 v = *(const f4*)(src + r * 64 + c4);
#pragma unroll
        for (int j = 0; j < 4; ++j) sT[r * 65 + c4 + j] = v[j];
    }
    __syncthreads();
#pragma unroll
    for (int p = 0; p < 2; ++p) {
        int idx = p * 256 + tid;
        int co = idx >> 3, g = (idx & 7) * 8;
        short8 o;
#pragma unroll
        for (int j = 0; j < 8; ++j) o[j] = (short)f2bf(sT[(g + j) * 65 + co]);
        *(short8*)(dst + (size_t)co * 64 + g) = o;
    }
}

// ---------------------------------------------------------------------------
// Kernel 1: split-K conv partials. Grid 256 = 8 ksplits x 32 mtiles.
// ---------------------------------------------------------------------------
__global__ __launch_bounds__(256) void conv_partial_kernel(
    const float* __restrict__ x, const u16* __restrict__ WsrT,
    float* __restrict__ partials)
{
    const int mtile  = blockIdx.x & 31;
    const int ksplit = blockIdx.x >> 5;
    const int tid  = threadIdx.x;
    const int wave = tid >> 6;
    const int lane = tid & 63;
    const int l15  = lane & 15;
    const int quad = lane >> 4;

    __shared__ u16 sA[64 * 72];
    __shared__ u16 sB[64 * 72];

    f32x4 acc[4];
#pragma unroll
    for (int nt = 0; nt < 4; ++nt) { acc[nt][0]=0.f; acc[nt][1]=0.f; acc[nt][2]=0.f; acc[nt][3]=0.f; }

    const int token0 = mtile * 64;
    for (int chunk = 0; chunk < 8; ++chunk) {
        const int cell = ksplit * 8 + chunk;
        const int py = cell >> 3, px = cell & 7;
        __syncthreads();
#pragma unroll
        for (int p = 0; p < 4; ++p) {
            int idx = p * 256 + tid;
            int r = idx >> 4, c4 = (idx & 15) * 4;
            int token = token0 + r;
            int b = token >> 8, rm = token & 255;
            int oy = rm >> 4, ox = rm & 15;
            int y = oy * 8 + py, xc = ox * 8 + px;
            f4 xv = *(const f4*)(x + ((size_t)(b * 16384 + y * 128 + xc)) * 64 + c4);
            short4v s;
#pragma unroll
            for (int j = 0; j < 4; ++j) s[j] = (short)f2bf(xv[j]);
            *(short4v*)&sA[r * 72 + c4] = s;
        }
#pragma unroll
        for (int p = 0; p < 2; ++p) {
            int idx = p * 256 + tid;
            int co = idx >> 3, g = (idx & 7) * 8;
            *(short8*)&sB[co * 72 + g] =
                *(const short8*)(WsrT + (size_t)cell * 4096 + co * 64 + g);
        }
        __syncthreads();
#pragma unroll
        for (int ks = 0; ks < 2; ++ks) {
            short8 af = *(const short8*)&sA[(wave * 16 + l15) * 72 + ks * 32 + quad * 8];
#pragma unroll
            for (int nt = 0; nt < 4; ++nt) {
                short8 bf = *(const short8*)&sB[(nt * 16 + l15) * 72 + ks * 32 + quad * 8];
                acc[nt] = MFMA16(af, bf, acc[nt]);
            }
        }
    }
    float* outp = partials + (size_t)ksplit * 131072;
#pragma unroll
    for (int nt = 0; nt < 4; ++nt)
#pragma unroll
        for (int i = 0; i < 4; ++i) {
            int row = token0 + wave * 16 + quad * 4 + i;
            outp[(size_t)row * 64 + nt * 16 + l15] = acc[nt][i];
        }
}

// ---------------------------------------------------------------------------
// Kernel 2: reduce partials + bias + LayerNorm + K/V proj (vector ALU).
// ---------------------------------------------------------------------------
__global__ __launch_bounds__(256) void lnkv_kernel(
    const float* __restrict__ partials, const float* __restrict__ bsr,
    const float* __restrict__ gamma, const float* __restrict__ beta,
    const float* __restrict__ Wk, const float* __restrict__ bk,
    const float* __restrict__ Wv, const float* __restrict__ bv,
    u16* __restrict__ kbuf, u16* __restrict__ vTbuf)
{
    const int wave = threadIdx.x >> 6;
    const int c    = threadIdx.x & 63;
    const int token = blockIdx.x * 4 + wave;

    float acc = 0.f;
#pragma unroll
    for (int s = 0; s < 8; ++s)
        acc += partials[(size_t)s * 131072 + (size_t)token * 64 + c];
    acc += bsr[c];

    float sum = acc, sumsq = acc * acc;
#pragma unroll
    for (int m = 1; m < 64; m <<= 1) {
        sum   += __shfl_xor(sum, m, 64);
        sumsq += __shfl_xor(sumsq, m, 64);
    }
    float mean = sum * (1.f / 64.f);
    float var  = sumsq * (1.f / 64.f) - mean * mean;
    float inv  = rsqrtf(var + 1e-5f);
    float xn   = (acc - mean) * inv * gamma[c] + beta[c];

    __shared__ float sxn[4][64];
    sxn[wave][c] = xn;

    float ka = bk[c], va = bv[c];
#pragma unroll 8
    for (int ci = 0; ci < 64; ++ci) {
        float xv = sxn[wave][ci];
        ka += xv * Wk[ci * 64 + c];
        va += xv * Wv[ci * 64 + c];
    }
    kbuf[(size_t)token * 64 + c] = f2bf(ka);
    int b = token >> 8, t = token & 255;
    vTbuf[(size_t)b * 16384 + c * 256 + t] = f2bf(va);
}

// ---------------------------------------------------------------------------
// Kernel 3: fused q-proj + attention + out-proj, all-transposed chain.
// Grid 512 (8 batches x 64 tiles of 256 q-rows), 512 thr = 8 waves,
// 32 q-rows/wave (2 q-tiles). Every stage computed transposed with
// mfma_f32_16x16x16bf16_1k so each C-output feeds the next MFMA as a
// B-operand directly in registers (B-frag layout == C-layout for K=16).
// LDS holds only K, V^T, Wq^T, Wp^T (A-operands); zero LDS round-trips.
// ---------------------------------------------------------------------------
__global__ __launch_bounds__(512) void attn_kernel(
    const float* __restrict__ x, const u16* __restrict__ WqT,
    const float* __restrict__ bq, const u16* __restrict__ WpT,
    const float* __restrict__ bp, const u16* __restrict__ kbuf,
    const u16* __restrict__ vTbuf, float* __restrict__ out)
{
    const int batch = blockIdx.x >> 6;
    const int row0  = (blockIdx.x & 63) * 256;
    const int tid  = threadIdx.x;
    const int wave = tid >> 6;
    const int lane = tid & 63;
    const int l15  = lane & 15;
    const int quad = lane >> 4;

    __shared__ u16 sK[256 * 72];      // k[token][d]      36.0 KB
    __shared__ u16 sV[64 * 264];      // vT[d][token]     33.8 KB
    __shared__ u16 sWq[64 * 72];      // Wq^T [co][ci]     9.0 KB
    __shared__ u16 sWp[64 * 72];      // Wp^T [co][ci]     9.0 KB

    // ---- staging (only barrier in the kernel) ----
#pragma unroll
    for (int p = 0; p < 4; ++p) {
        int idx = p * 512 + tid; int tt = idx >> 3, seg = idx & 7;
        *(short8*)&sK[tt * 72 + seg * 8] =
            *(const short8*)(kbuf + ((size_t)(batch * 256 + tt)) * 64 + seg * 8);
    }
#pragma unroll
    for (int p = 0; p < 4; ++p) {
        int idx = p * 512 + tid; int d = idx >> 5, seg = idx & 31;
        *(short8*)&sV[d * 264 + seg * 8] =
            *(const short8*)(vTbuf + ((size_t)(batch * 64 + d)) * 256 + seg * 8);
    }
    {
        int co = tid >> 3, g = (tid & 7) * 8;
        *(short8*)&sWq[co * 72 + g] = *(const short8*)(WqT + (size_t)co * 64 + g);
        *(short8*)&sWp[co * 72 + g] = *(const short8*)(WpT + (size_t)co * 64 + g);
    }
    __syncthreads();

    const int qbase = row0 + wave * 32;   // this wave's 32 q-rows

    // ---- q^T = Wq^T @ x^T  (A from sWq; B = x read straight from global) ----
    f32x4 qT[2][4];
#pragma unroll
    for (int qt = 0; qt < 2; ++qt)
#pragma unroll
        for (int ct = 0; ct < 4; ++ct) { qT[qt][ct][0]=0.f; qT[qt][ct][1]=0.f; qT[qt][ct][2]=0.f; qT[qt][ct][3]=0.f; }
#pragma unroll
    for (int kt = 0; kt < 4; ++kt) {
        short4v bfr[2];
#pragma unroll
        for (int qt = 0; qt < 2; ++qt) {
            f4 xv = *(const f4*)(x + ((size_t)(batch * 16384 + qbase + qt * 16 + l15)) * 64 + kt * 16 + quad * 4);
            bfr[qt] = pack4(xv);
        }
#pragma unroll
        for (int ct = 0; ct < 4; ++ct) {
            short4v a = *(const short4v*)&sWq[(ct * 16 + l15) * 72 + kt * 16 + quad * 4];
#pragma unroll
            for (int qt = 0; qt < 2; ++qt) qT[qt][ct] = MFMA1K(a, bfr[qt], qT[qt][ct]);
        }
    }
    // bias + 1/sqrt(64), convert to B-frags for S^T
    short4v qf[2][4];
#pragma unroll
    for (int ct = 0; ct < 4; ++ct) {
        f4 bqv = *(const f4*)(bq + ct * 16 + quad * 4);
#pragma unroll
        for (int qt = 0; qt < 2; ++qt) {
            f4 t;
#pragma unroll
            for (int i = 0; i < 4; ++i) t[i] = (qT[qt][ct][i] + bqv[i]) * 0.125f;
            qf[qt][ct] = pack4(t);
        }
    }

    // ---- S^T = K @ q^T  (A from sK; B = qf in registers) ----
    f32x4 st[2][16];
#pragma unroll
    for (int qt = 0; qt < 2; ++qt)
#pragma unroll
        for (int mt = 0; mt < 16; ++mt) { st[qt][mt][0]=0.f; st[qt][mt][1]=0.f; st[qt][mt][2]=0.f; st[qt][mt][3]=0.f; }
#pragma unroll
    for (int mt = 0; mt < 16; ++mt)
#pragma unroll
        for (int kt = 0; kt < 4; ++kt) {
            short4v a = *(const short4v*)&sK[(mt * 16 + l15) * 72 + kt * 16 + quad * 4];
#pragma unroll
            for (int qt = 0; qt < 2; ++qt) st[qt][mt] = MFMA1K(a, qf[qt][kt], st[qt][mt]);
        }

    // ---- softmax over k (rows of S^T): in-lane 64 + 2 cross-quad shuffles ----
    short4v pf[2][16];
    float linv[2];
#pragma unroll
    for (int qt = 0; qt < 2; ++qt) {
        float mx = -1e30f;
#pragma unroll
        for (int mt = 0; mt < 16; ++mt)
#pragma unroll
            for (int i = 0; i < 4; ++i) mx = fmaxf(mx, st[qt][mt][i]);
        mx = fmaxf(mx, __shfl_xor(mx, 16, 64));
        mx = fmaxf(mx, __shfl_xor(mx, 32, 64));
        float l = 0.f;
#pragma unroll
        for (int mt = 0; mt < 16; ++mt) {
            f4 e;
#pragma unroll
            for (int i = 0; i < 4; ++i) { e[i] = __expf(st[qt][mt][i] - mx); l += e[i]; }
            pf[qt][mt] = pack4(e);
        }
        l += __shfl_xor(l, 16, 64);
        l += __shfl_xor(l, 32, 64);
        linv[qt] = 1.0f / l;
    }

    // ---- O^T = V^T @ P^T  (A from sV; B = pf in registers) ----
    f32x4 ot[2][4];
#pragma unroll
    for (int qt = 0; qt < 2; ++qt)
#pragma unroll
        for (int dt = 0; dt < 4; ++dt) { ot[qt][dt][0]=0.f; ot[qt][dt][1]=0.f; ot[qt][dt][2]=0.f; ot[qt][dt][3]=0.f; }
#pragma unroll
    for (int mt = 0; mt < 16; ++mt)
#pragma unroll
        for (int dt = 0; dt < 4; ++dt) {
            short4v a = *(const short4v*)&sV[(dt * 16 + l15) * 264 + mt * 16 + quad * 4];
#pragma unroll
            for (int qt = 0; qt < 2; ++qt) ot[qt][dt] = MFMA1K(a, pf[qt][mt], ot[qt][dt]);
        }

    // ---- final^T = Wp^T @ (O^T / l)  (A from sWp; B in registers) ----
    short4v of[2][4];
#pragma unroll
    for (int dt = 0; dt < 4; ++dt)
#pragma unroll
        for (int qt = 0; qt < 2; ++qt) {
            f4 t;
#pragma unroll
            for (int i = 0; i < 4; ++i) t[i] = ot[qt][dt][i] * linv[qt];
            of[qt][dt] = pack4(t);
        }
    f32x4 ft[2][4];
#pragma unroll
    for (int qt = 0; qt < 2; ++qt)
#pragma unroll
        for (int ct = 0; ct < 4; ++ct) { ft[qt][ct][0]=0.f; ft[qt][ct][1]=0.f; ft[qt][ct][2]=0.f; ft[qt][ct][3]=0.f; }
#pragma unroll
    for (int kt = 0; kt < 4; ++kt)
#pragma unroll
        for (int ct = 0; ct < 4; ++ct) {
            short4v a = *(const short4v*)&sWp[(ct * 16 + l15) * 72 + kt * 16 + quad * 4];
#pragma unroll
            for (int qt = 0; qt < 2; ++qt) ft[qt][ct] = MFMA1K(a, of[qt][kt], ft[qt][ct]);
        }

    // ---- store: lane holds 4 consecutive channels of one row -> dwordx4 ----
#pragma unroll
    for (int ct = 0; ct < 4; ++ct) {
        f4 bpv = *(const f4*)(bp + ct * 16 + quad * 4);
#pragma unroll
        for (int qt = 0; qt < 2; ++qt) {
            f4 r;
#pragma unroll
            for (int i = 0; i < 4; ++i) r[i] = ft[qt][ct][i] + bpv[i];
            *(f4*)(out + ((size_t)(batch * 16384 + qbase + qt * 16 + l15)) * 64 + ct * 16 + quad * 4) = r;
        }
    }
}

// ---------------------------------------------------------------------------
extern "C" void kernel_launch(void* const* d_in, const int* in_sizes, int n_in,
                              void* d_out, int out_size, void* d_ws, size_t ws_size,
                              hipStream_t stream) {
    const float* x     = (const float*)d_in[0];
    const float* Wq    = (const float*)d_in[1];
    const float* bq    = (const float*)d_in[2];
    const float* Wk    = (const float*)d_in[3];
    const float* bk    = (const float*)d_in[4];
    const float* Wv    = (const float*)d_in[5];
    const float* bv    = (const float*)d_in[6];
    const float* Wsr   = (const float*)d_in[7];
    const float* bsr   = (const float*)d_in[8];
    const float* gamma = (const float*)d_in[9];
    const float* beta  = (const float*)d_in[10];
    const float* Wp    = (const float*)d_in[11];
    const float* bp    = (const float*)d_in[12];

    char* w = (char*)d_ws;
    float* partials = (float*)w;                         // 8*2048*64 f32 = 4 MB
    u16* kbuf  = (u16*)(w + 4194304);                    // 256 KB
    u16* vTbuf = (u16*)(w + 4194304 + 262144);           // 256 KB
    u16* WsrT  = (u16*)(w + 4194304 + 524288);           // 512 KB
    u16* WqT   = (u16*)(w + 4194304 + 524288 + 524288);  // 8 KB
    u16* WpT   = (u16*)(w + 4194304 + 524288 + 524288 + 8192);
    float* out = (float*)d_out;

    prep_kernel<<<66, 256, 0, stream>>>(Wsr, Wq, Wp, WsrT, WqT, WpT);
    conv_partial_kernel<<<256, 256, 0, stream>>>(x, WsrT, partials);
    lnkv_kernel<<<512, 256, 0, stream>>>(partials, bsr, gamma, beta, Wk, bk, Wv, bv, kbuf, vTbuf);
    attn_kernel<<<512, 512, 0, stream>>>(x, WqT, bq, WpT, bp, kbuf, vTbuf, out);
}

// Round 7
// 144.830 us; speedup vs baseline: 1.6326x; 1.0248x over previous
//
#include <hip/hip_runtime.h>

typedef unsigned short u16;
typedef short short8 __attribute__((ext_vector_type(8)));
typedef short short4v __attribute__((ext_vector_type(4)));
typedef float f32x4 __attribute__((ext_vector_type(4)));
typedef float f4 __attribute__((ext_vector_type(4)));

#define MFMA16(a, b, c) __builtin_amdgcn_mfma_f32_16x16x32_bf16(a, b, c, 0, 0, 0)
// K=16 variant: B-fragment layout == C/D layout -> chain MFMAs in registers
#define MFMA1K(a, b, c) __builtin_amdgcn_mfma_f32_16x16x16bf16_1k(a, b, c, 0, 0, 0)

__device__ inline u16 f2bf(float f) {
    unsigned int v = __builtin_bit_cast(unsigned int, f);
    unsigned int r = (v + 0x7FFFu + ((v >> 16) & 1u)) >> 16;
    return (u16)r;
}
__device__ inline short4v pack4(f4 v) {
    short4v r;
#pragma unroll
    for (int j = 0; j < 4; ++j) r[j] = (short)f2bf(v[j]);
    return r;
}

// ---------------------------------------------------------------------------
// Kernel 0: one-time weight prep. Transpose Wsr (per tap), Wq, Wp to bf16
// [co][ci] row-major in ws. Grid 66: bid<64 = tap, 64 = Wq, 65 = Wp.
// ---------------------------------------------------------------------------
__global__ __launch_bounds__(256) void prep_kernel(
    const float* __restrict__ Wsr, const float* __restrict__ Wq,
    const float* __restrict__ Wp,
    u16* __restrict__ WsrT, u16* __restrict__ WqT, u16* __restrict__ WpT)
{
    const int bid = blockIdx.x;
    const int tid = threadIdx.x;
    __shared__ float sT[64 * 65];
    const float* src;
    u16* dst;
    if (bid < 64)      { src = Wsr + (size_t)bid * 4096; dst = WsrT + (size_t)bid * 4096; }
    else if (bid == 64){ src = Wq;  dst = WqT; }
    else               { src = Wp;  dst = WpT; }
#pragma unroll
    for (int p = 0; p < 4; ++p) {
        int idx = p * 256 + tid;
        int r = idx >> 4, c4 = (idx & 15) * 4;
        f4 v = *(const f4*)(src + r * 64 + c4);
#pragma unroll
        for (int j = 0; j < 4; ++j) sT[r * 65 + c4 + j] = v[j];
    }
    __syncthreads();
#pragma unroll
    for (int p = 0; p < 2; ++p) {
        int idx = p * 256 + tid;
        int co = idx >> 3, g = (idx & 7) * 8;
        short8 o;
#pragma unroll
        for (int j = 0; j < 8; ++j) o[j] = (short)f2bf(sT[(g + j) * 65 + co]);
        *(short8*)(dst + (size_t)co * 64 + g) = o;
    }
}

// ---------------------------------------------------------------------------
// Kernel 1: split-K conv partials. Grid 512 = 16 ksplits x 32 mtiles
// (2 blocks/CU for latency hiding, 4 serial taps each).
// fp32 partials [16][2048][64].
// ---------------------------------------------------------------------------
__global__ __launch_bounds__(256) void conv_partial_kernel(
    const float* __restrict__ x, const u16* __restrict__ WsrT,
    float* __restrict__ partials)
{
    const int mtile  = blockIdx.x & 31;
    const int ksplit = blockIdx.x >> 5;
    const int tid  = threadIdx.x;
    const int wave = tid >> 6;
    const int lane = tid & 63;
    const int l15  = lane & 15;
    const int quad = lane >> 4;

    __shared__ u16 sA[64 * 72];
    __shared__ u16 sB[64 * 72];

    f32x4 acc[4];
#pragma unroll
    for (int nt = 0; nt < 4; ++nt) { acc[nt][0]=0.f; acc[nt][1]=0.f; acc[nt][2]=0.f; acc[nt][3]=0.f; }

    const int token0 = mtile * 64;
    for (int chunk = 0; chunk < 4; ++chunk) {
        const int cell = ksplit * 4 + chunk;
        const int py = cell >> 3, px = cell & 7;
        __syncthreads();
#pragma unroll
        for (int p = 0; p < 4; ++p) {
            int idx = p * 256 + tid;
            int r = idx >> 4, c4 = (idx & 15) * 4;
            int token = token0 + r;
            int b = token >> 8, rm = token & 255;
            int oy = rm >> 4, ox = rm & 15;
            int y = oy * 8 + py, xc = ox * 8 + px;
            f4 xv = *(const f4*)(x + ((size_t)(b * 16384 + y * 128 + xc)) * 64 + c4);
            short4v s;
#pragma unroll
            for (int j = 0; j < 4; ++j) s[j] = (short)f2bf(xv[j]);
            *(short4v*)&sA[r * 72 + c4] = s;
        }
#pragma unroll
        for (int p = 0; p < 2; ++p) {
            int idx = p * 256 + tid;
            int co = idx >> 3, g = (idx & 7) * 8;
            *(short8*)&sB[co * 72 + g] =
                *(const short8*)(WsrT + (size_t)cell * 4096 + co * 64 + g);
        }
        __syncthreads();
#pragma unroll
        for (int ks = 0; ks < 2; ++ks) {
            short8 af = *(const short8*)&sA[(wave * 16 + l15) * 72 + ks * 32 + quad * 8];
#pragma unroll
            for (int nt = 0; nt < 4; ++nt) {
                short8 bf = *(const short8*)&sB[(nt * 16 + l15) * 72 + ks * 32 + quad * 8];
                acc[nt] = MFMA16(af, bf, acc[nt]);
            }
        }
    }
    float* outp = partials + (size_t)ksplit * 131072;
#pragma unroll
    for (int nt = 0; nt < 4; ++nt)
#pragma unroll
        for (int i = 0; i < 4; ++i) {
            int row = token0 + wave * 16 + quad * 4 + i;
            outp[(size_t)row * 64 + nt * 16 + l15] = acc[nt][i];
        }
}

// ---------------------------------------------------------------------------
// Kernel 2: reduce 16 partials + bias + LayerNorm + K/V proj (vector ALU).
// Grid 512 x 256 thr; one wave per kv token. No barriers.
// ---------------------------------------------------------------------------
__global__ __launch_bounds__(256) void lnkv_kernel(
    const float* __restrict__ partials, const float* __restrict__ bsr,
    const float* __restrict__ gamma, const float* __restrict__ beta,
    const float* __restrict__ Wk, const float* __restrict__ bk,
    const float* __restrict__ Wv, const float* __restrict__ bv,
    u16* __restrict__ kbuf, u16* __restrict__ vTbuf)
{
    const int wave = threadIdx.x >> 6;
    const int c    = threadIdx.x & 63;
    const int token = blockIdx.x * 4 + wave;

    float acc = 0.f;
#pragma unroll
    for (int s = 0; s < 16; ++s)
        acc += partials[(size_t)s * 131072 + (size_t)token * 64 + c];
    acc += bsr[c];

    float sum = acc, sumsq = acc * acc;
#pragma unroll
    for (int m = 1; m < 64; m <<= 1) {
        sum   += __shfl_xor(sum, m, 64);
        sumsq += __shfl_xor(sumsq, m, 64);
    }
    float mean = sum * (1.f / 64.f);
    float var  = sumsq * (1.f / 64.f) - mean * mean;
    float inv  = rsqrtf(var + 1e-5f);
    float xn   = (acc - mean) * inv * gamma[c] + beta[c];

    __shared__ float sxn[4][64];
    sxn[wave][c] = xn;

    float ka = bk[c], va = bv[c];
#pragma unroll 8
    for (int ci = 0; ci < 64; ++ci) {
        float xv = sxn[wave][ci];
        ka += xv * Wk[ci * 64 + c];
        va += xv * Wv[ci * 64 + c];
    }
    kbuf[(size_t)token * 64 + c] = f2bf(ka);
    int b = token >> 8, t = token & 255;
    vTbuf[(size_t)b * 16384 + c * 256 + t] = f2bf(va);
}

// ---------------------------------------------------------------------------
// Kernel 3: fused q-proj + attention + out-proj, all-transposed chain.
// Grid 512 (8 batches x 64 tiles of 256 q-rows), 512 thr = 8 waves,
// 32 q-rows/wave. mfma_f32_16x16x16bf16_1k: C-output feeds next MFMA as
// B-operand directly in registers. LDS holds only A-operands.
// ---------------------------------------------------------------------------
__global__ __launch_bounds__(512) void attn_kernel(
    const float* __restrict__ x, const u16* __restrict__ WqT,
    const float* __restrict__ bq, const u16* __restrict__ WpT,
    const float* __restrict__ bp, const u16* __restrict__ kbuf,
    const u16* __restrict__ vTbuf, float* __restrict__ out)
{
    const int batch = blockIdx.x >> 6;
    const int row0  = (blockIdx.x & 63) * 256;
    const int tid  = threadIdx.x;
    const int wave = tid >> 6;
    const int lane = tid & 63;
    const int l15  = lane & 15;
    const int quad = lane >> 4;

    __shared__ u16 sK[256 * 72];      // k[token][d]      36.0 KB
    __shared__ u16 sV[64 * 264];      // vT[d][token]     33.8 KB
    __shared__ u16 sWq[64 * 72];      // Wq^T [co][ci]     9.0 KB
    __shared__ u16 sWp[64 * 72];      // Wp^T [co][ci]     9.0 KB

    // ---- staging (only barrier in the kernel) ----
#pragma unroll
    for (int p = 0; p < 4; ++p) {
        int idx = p * 512 + tid; int tt = idx >> 3, seg = idx & 7;
        *(short8*)&sK[tt * 72 + seg * 8] =
            *(const short8*)(kbuf + ((size_t)(batch * 256 + tt)) * 64 + seg * 8);
    }
#pragma unroll
    for (int p = 0; p < 4; ++p) {
        int idx = p * 512 + tid; int d = idx >> 5, seg = idx & 31;
        *(short8*)&sV[d * 264 + seg * 8] =
            *(const short8*)(vTbuf + ((size_t)(batch * 64 + d)) * 256 + seg * 8);
    }
    {
        int co = tid >> 3, g = (tid & 7) * 8;
        *(short8*)&sWq[co * 72 + g] = *(const short8*)(WqT + (size_t)co * 64 + g);
        *(short8*)&sWp[co * 72 + g] = *(const short8*)(WpT + (size_t)co * 64 + g);
    }
    __syncthreads();

    const int qbase = row0 + wave * 32;   // this wave's 32 q-rows

    // ---- q^T = Wq^T @ x^T  (A from sWq; B = x read straight from global) ----
    f32x4 qT[2][4];
#pragma unroll
    for (int qt = 0; qt < 2; ++qt)
#pragma unroll
        for (int ct = 0; ct < 4; ++ct) { qT[qt][ct][0]=0.f; qT[qt][ct][1]=0.f; qT[qt][ct][2]=0.f; qT[qt][ct][3]=0.f; }
#pragma unroll
    for (int kt = 0; kt < 4; ++kt) {
        short4v bfr[2];
#pragma unroll
        for (int qt = 0; qt < 2; ++qt) {
            f4 xv = *(const f4*)(x + ((size_t)(batch * 16384 + qbase + qt * 16 + l15)) * 64 + kt * 16 + quad * 4);
            bfr[qt] = pack4(xv);
        }
#pragma unroll
        for (int ct = 0; ct < 4; ++ct) {
            short4v a = *(const short4v*)&sWq[(ct * 16 + l15) * 72 + kt * 16 + quad * 4];
#pragma unroll
            for (int qt = 0; qt < 2; ++qt) qT[qt][ct] = MFMA1K(a, bfr[qt], qT[qt][ct]);
        }
    }
    // bias + 1/sqrt(64), convert to B-frags for S^T
    short4v qf[2][4];
#pragma unroll
    for (int ct = 0; ct < 4; ++ct) {
        f4 bqv = *(const f4*)(bq + ct * 16 + quad * 4);
#pragma unroll
        for (int qt = 0; qt < 2; ++qt) {
            f4 t;
#pragma unroll
            for (int i = 0; i < 4; ++i) t[i] = (qT[qt][ct][i] + bqv[i]) * 0.125f;
            qf[qt][ct] = pack4(t);
        }
    }

    // ---- S^T = K @ q^T  (A from sK; B = qf in registers) ----
    f32x4 st[2][16];
#pragma unroll
    for (int qt = 0; qt < 2; ++qt)
#pragma unroll
        for (int mt = 0; mt < 16; ++mt) { st[qt][mt][0]=0.f; st[qt][mt][1]=0.f; st[qt][mt][2]=0.f; st[qt][mt][3]=0.f; }
#pragma unroll
    for (int mt = 0; mt < 16; ++mt)
#pragma unroll
        for (int kt = 0; kt < 4; ++kt) {
            short4v a = *(const short4v*)&sK[(mt * 16 + l15) * 72 + kt * 16 + quad * 4];
#pragma unroll
            for (int qt = 0; qt < 2; ++qt) st[qt][mt] = MFMA1K(a, qf[qt][kt], st[qt][mt]);
        }

    // ---- softmax over k (rows of S^T): in-lane 64 + 2 cross-quad shuffles ----
    short4v pf[2][16];
    float linv[2];
#pragma unroll
    for (int qt = 0; qt < 2; ++qt) {
        float mx = -1e30f;
#pragma unroll
        for (int mt = 0; mt < 16; ++mt)
#pragma unroll
            for (int i = 0; i < 4; ++i) mx = fmaxf(mx, st[qt][mt][i]);
        mx = fmaxf(mx, __shfl_xor(mx, 16, 64));
        mx = fmaxf(mx, __shfl_xor(mx, 32, 64));
        float l = 0.f;
#pragma unroll
        for (int mt = 0; mt < 16; ++mt) {
            f4 e;
#pragma unroll
            for (int i = 0; i < 4; ++i) { e[i] = __expf(st[qt][mt][i] - mx); l += e[i]; }
            pf[qt][mt] = pack4(e);
        }
        l += __shfl_xor(l, 16, 64);
        l += __shfl_xor(l, 32, 64);
        linv[qt] = 1.0f / l;
    }

    // ---- O^T = V^T @ P^T  (A from sV; B = pf in registers) ----
    f32x4 ot[2][4];
#pragma unroll
    for (int qt = 0; qt < 2; ++qt)
#pragma unroll
        for (int dt = 0; dt < 4; ++dt) { ot[qt][dt][0]=0.f; ot[qt][dt][1]=0.f; ot[qt][dt][2]=0.f; ot[qt][dt][3]=0.f; }
#pragma unroll
    for (int mt = 0; mt < 16; ++mt)
#pragma unroll
        for (int dt = 0; dt < 4; ++dt) {
            short4v a = *(const short4v*)&sV[(dt * 16 + l15) * 264 + mt * 16 + quad * 4];
#pragma unroll
            for (int qt = 0; qt < 2; ++qt) ot[qt][dt] = MFMA1K(a, pf[qt][mt], ot[qt][dt]);
        }

    // ---- final^T = Wp^T @ (O^T / l)  (A from sWp; B in registers) ----
    short4v of[2][4];
#pragma unroll
    for (int dt = 0; dt < 4; ++dt)
#pragma unroll
        for (int qt = 0; qt < 2; ++qt) {
            f4 t;
#pragma unroll
            for (int i = 0; i < 4; ++i) t[i] = ot[qt][dt][i] * linv[qt];
            of[qt][dt] = pack4(t);
        }
    f32x4 ft[2][4];
#pragma unroll
    for (int qt = 0; qt < 2; ++qt)
#pragma unroll
        for (int ct = 0; ct < 4; ++ct) { ft[qt][ct][0]=0.f; ft[qt][ct][1]=0.f; ft[qt][ct][2]=0.f; ft[qt][ct][3]=0.f; }
#pragma unroll
    for (int kt = 0; kt < 4; ++kt)
#pragma unroll
        for (int ct = 0; ct < 4; ++ct) {
            short4v a = *(const short4v*)&sWp[(ct * 16 + l15) * 72 + kt * 16 + quad * 4];
#pragma unroll
            for (int qt = 0; qt < 2; ++qt) ft[qt][ct] = MFMA1K(a, of[qt][kt], ft[qt][ct]);
        }

    // ---- store: lane holds 4 consecutive channels of one row -> dwordx4 ----
#pragma unroll
    for (int ct = 0; ct < 4; ++ct) {
        f4 bpv = *(const f4*)(bp + ct * 16 + quad * 4);
#pragma unroll
        for (int qt = 0; qt < 2; ++qt) {
            f4 r;
#pragma unroll
            for (int i = 0; i < 4; ++i) r[i] = ft[qt][ct][i] + bpv[i];
            *(f4*)(out + ((size_t)(batch * 16384 + qbase + qt * 16 + l15)) * 64 + ct * 16 + quad * 4) = r;
        }
    }
}

// ---------------------------------------------------------------------------
extern "C" void kernel_launch(void* const* d_in, const int* in_sizes, int n_in,
                              void* d_out, int out_size, void* d_ws, size_t ws_size,
                              hipStream_t stream) {
    const float* x     = (const float*)d_in[0];
    const float* Wq    = (const float*)d_in[1];
    const float* bq    = (const float*)d_in[2];
    const float* Wk    = (const float*)d_in[3];
    const float* bk    = (const float*)d_in[4];
    const float* Wv    = (const float*)d_in[5];
    const float* bv    = (const float*)d_in[6];
    const float* Wsr   = (const float*)d_in[7];
    const float* bsr   = (const float*)d_in[8];
    const float* gamma = (const float*)d_in[9];
    const float* beta  = (const float*)d_in[10];
    const float* Wp    = (const float*)d_in[11];
    const float* bp    = (const float*)d_in[12];

    char* w = (char*)d_ws;
    float* partials = (float*)w;                         // 16*2048*64 f32 = 8.4 MB
    u16* kbuf  = (u16*)(w + 8388608);                    // 256 KB
    u16* vTbuf = (u16*)(w + 8388608 + 262144);           // 256 KB
    u16* WsrT  = (u16*)(w + 8388608 + 524288);           // 512 KB
    u16* WqT   = (u16*)(w + 8388608 + 524288 + 524288);  // 8 KB
    u16* WpT   = (u16*)(w + 8388608 + 524288 + 524288 + 8192);
    float* out = (float*)d_out;

    prep_kernel<<<66, 256, 0, stream>>>(Wsr, Wq, Wp, WsrT, WqT, WpT);
    conv_partial_kernel<<<512, 256, 0, stream>>>(x, WsrT, partials);
    lnkv_kernel<<<512, 256, 0, stream>>>(partials, bsr, gamma, beta, Wk, bk, Wv, bv, kbuf, vTbuf);
    attn_kernel<<<512, 512, 0, stream>>>(x, WqT, bq, WpT, bp, kbuf, vTbuf, out);
}